// Round 4
// baseline (607.326 us; speedup 1.0000x reference)
//
#include <hip/hip_runtime.h>
#include <hip/hip_bf16.h>

// Problem constants
#define NB   8      // batch
#define NH   252    // height
#define NW   192    // width
#define NC   64     // channels
#define NE   192    // embed
#define NO   486    // K^4 * HEADS
#define NWIN (NB*84*64)     // 43008 windows
#define SCALE_F 0.17677669529663687f  // 32^-0.5

typedef __bf16 bf16x8 __attribute__((ext_vector_type(8)));
typedef __bf16 bf16x4 __attribute__((ext_vector_type(4)));
typedef float floatx4 __attribute__((ext_vector_type(4)));

// Precomputed weights (bf16, written by kt_prep each call):
//   g_WT[e][h*64+c]  = sum_d v_w[c][h*32+d] * out_w[h*32+d][e]   (fused V+output proj)
//   g_awT[n][c]      = attn_w[c][n]                               (logit weights, transposed)
__device__ __attribute__((aligned(16))) __hip_bfloat16 g_WT[NE * 384];
__device__ __attribute__((aligned(16))) __hip_bfloat16 g_awT[NO * 64];

__device__ __forceinline__ bf16x8 bf16x8_zero() {
    bf16x8 z;
    #pragma unroll
    for (int j = 0; j < 8; ++j) z[j] = (__bf16)0.f;
    return z;
}

// Per-M-tile K-slice offset for the stride-10 block-diagonal layout.
// off = clamp(16t-8, 0, 48) -> {0,8,24,40,48}; max used col = 30 < 32.
__device__ __forceinline__ int koff(int t) {
    int v = 16 * t - 8;
    v = v < 0 ? 0 : v;
    return v > 48 ? 48 : v;
}

// XOR-16 swizzled index into xwT[64][128]: row c (256 B = 16 blocks of 16 B),
// pixel p lives in block (p>>3)^(c&15), halfword (p&7).
__device__ __forceinline__ int xw_idx(int c, int p) {
    return c * 128 + ((((p) >> 3) ^ (c & 15)) << 3) + ((p) & 7);
}

// 8B-aligned bf16x8 load as two b64s (for 72/136-byte row strides).
__device__ __forceinline__ bf16x8 ld_b64x2(const __bf16* p) {
    union { bf16x4 h[2]; bf16x8 v; } u;
    u.h[0] = *(const bf16x4*)p;
    u.h[1] = *(const bf16x4*)(p + 4);
    return u.v;
}

// ---------------------------------------------------------------------------
// Kernel T: build g_WT (fp32 accumulate of v_w @ out_w per head, then bf16)
// and g_awT (transpose+cvt of attn_w).
// ---------------------------------------------------------------------------
__global__ __launch_bounds__(256) void kt_prep(
    const float* __restrict__ vw, const float* __restrict__ ow,
    const float* __restrict__ aw)
{
    int t = blockIdx.x * 256 + threadIdx.x;
    if (t < NE * 384) {
        int e  = t / 384;
        int hc = t - e * 384;        // h*64 + c
        int h  = hc >> 6;
        int c  = hc & 63;
        float s = 0.f;
        #pragma unroll
        for (int d = 0; d < 32; ++d)
            s = fmaf(vw[c * NE + h * 32 + d], ow[(h * 32 + d) * NE + e], s);
        g_WT[e * 384 + hc] = __float2bfloat16(s);
    } else {
        int tt = t - NE * 384;
        if (tt < NO * 64) {
            int n = tt >> 6;
            int c = tt & 63;
            g_awT[tt] = __float2bfloat16(aw[c * NO + n]);
        }
    }
}

// ---------------------------------------------------------------------------
// Kernel A (fused, barrier-economical): per block = 8 windows (72 pixels in
// 80 stride-10 slots).  10 barriers per block (was 17):
//   ph0:  x -> xwT (swizzled) ; zero attnBD6                        [sync]
//   ph0.5: pooled = mean of 9 px                                    [sync]
//   ph1:  logits MFMA -> attnS                                      [sync]
//   ph2:  FUSED softmax+scatter: probs written straight into the
//         all-heads block-diag attnBD6; bfragX hoisted here         [sync]
//   B(0) -> Ph0                                                     [sync]
//   h=0..5: C(h) reads Ph[h&1] (+35 MFMA) || B(h+1) -> Ph[!(h&1)]   [sync x5]
//   epilogue: accF + bias -> out
// LDS overlays (59872 B total, 2 blocks/CU):
//   [0,16384)      xwT[64][128]   (dead after bfragX hoist)
//   [0,10880)      Ph0[80][68]    (live from B(0))
//   [13280,24160)  Ph1[80][68]    (live from B(1); over xwT tail + attnS)
//   [16384,24160)  attnS[8][486]  (dead after ph2)
//   [24160,25312)  pooled[8][72]
//   [25312,59872)  attnBD6[6][5][16][36]
// ---------------------------------------------------------------------------
#define OFF_XWT   0
#define OFF_PH0   0
#define OFF_PH1   13280
#define OFF_ATTNS 16384
#define OFF_POOL  24160
#define OFF_BD    25312
#define SMEM_BYTES 59872

__global__ __launch_bounds__(256, 2) void ka_fused(
    const float* __restrict__ x,
    const float* __restrict__ attn_b,
    const float* __restrict__ out_b,
    float* __restrict__ out)
{
    __shared__ __attribute__((aligned(16))) unsigned char smem[SMEM_BYTES];
    __bf16* xwT    = (__bf16*)(smem + OFF_XWT);
    __bf16* ph0b   = (__bf16*)(smem + OFF_PH0);
    __bf16* ph1b   = (__bf16*)(smem + OFF_PH1);
    __bf16* attnS  = (__bf16*)(smem + OFF_ATTNS);
    __bf16* pooled = (__bf16*)(smem + OFF_POOL);
    __bf16* bd     = (__bf16*)(smem + OFF_BD);

    const int tid  = threadIdx.x;
    const int lane = tid & 63;
    const int wv   = tid >> 6;
    const int m16  = lane & 15;
    const int quad = lane >> 4;
    const int wbase = blockIdx.x * 8;

    // All 8 windows of a block share (b, i); j = jB + win (5376 % 8 == 0).
    const int bB   = wbase / 5376;
    const int remB = wbase - bB * 5376;
    const int iB   = remB >> 6;
    const int jB   = remB & 63;
    const int xbase = ((bB * NH + iB * 3) * NW + jB * 3) * NC;

    // --- ph0: load x (coalesced over c=lane) -> swizzled xwT; zero attnBD6 ---
    #pragma unroll
    for (int i = 0; i < 5; ++i) {
        int b4 = i * 4 + wv;                 // 4-pixel group 0..19
        bf16x4 pk;
        #pragma unroll
        for (int s = 0; s < 4; ++s) {
            int p10 = b4 * 4 + s;
            int w = p10 / 10;
            int q = p10 - w * 10;
            float xv = 0.f;
            if (q < 9) {                     // wave-uniform branch
                int pr = q / 3;
                int pc = q - pr * 3;
                xv = x[xbase + (pr * NW + w * 3 + pc) * NC + lane];
            }
            pk[s] = (__bf16)xv;
        }
        *(bf16x4*)(&xwT[lane * 128 + (((b4 >> 1) ^ (lane & 15)) << 3) + (b4 & 1) * 4]) = pk;
    }
    #pragma unroll
    for (int i = 0; i < 9; ++i) {
        int ch = i * 256 + tid;              // 16B chunks: 34560/16 = 2160
        if (ch < 2160) *(uint4*)(&bd[ch * 8]) = make_uint4(0u, 0u, 0u, 0u);
    }
    __syncthreads();

    // --- ph0.5: pooled = mean over 9 pixels ---
    #pragma unroll
    for (int i = 0; i < 2; ++i) {
        int win = i * 4 + wv;
        float s = 0.f;
        #pragma unroll
        for (int q = 0; q < 9; ++q) s += (float)xwT[xw_idx(lane, win * 10 + q)];
        pooled[win * 72 + lane] = (__bf16)(s * (1.f / 9.f));
    }
    __syncthreads();

    // --- ph1: logits via MFMA -> attnS ---
    {
        bf16x8 afragP[2];
        #pragma unroll
        for (int ks = 0; ks < 2; ++ks)      // A rows 8..15 read overrun garbage, discarded
            afragP[ks] = *(const bf16x8*)(&pooled[m16 * 72 + ks * 32 + quad * 8]);
        const __bf16* Aw = (const __bf16*)g_awT;
        #pragma unroll
        for (int i = 0; i < 8; ++i) {
            int tile = wv * 8 + i;           // 31 tiles of 16 cover N=486
            int n = tile * 16 + m16;
            bool nvalid = (tile < 31) && (n < NO);
            bf16x8 b0 = nvalid ? *(const bf16x8*)(Aw + n * 64 + quad * 8)      : bf16x8_zero();
            bf16x8 b1 = nvalid ? *(const bf16x8*)(Aw + n * 64 + 32 + quad * 8) : bf16x8_zero();
            floatx4 acc;
            acc[0] = 0.f; acc[1] = 0.f; acc[2] = 0.f; acc[3] = 0.f;
            acc = __builtin_amdgcn_mfma_f32_16x16x32_bf16(afragP[0], b0, acc, 0, 0, 0);
            acc = __builtin_amdgcn_mfma_f32_16x16x32_bf16(afragP[1], b1, acc, 0, 0, 0);
            if (nvalid && quad < 2) {        // D rows 0..7 = windows
                float bn = attn_b[n];
                #pragma unroll
                for (int r = 0; r < 4; ++r)
                    attnS[(quad * 4 + r) * 486 + n] = (__bf16)((acc[r] + bn) * SCALE_F);
            }
        }
    }
    __syncthreads();

    // --- ph2: FUSED softmax + scatter into attnBD6; hoist bfragX ---
    bf16x8 bfragX[5];                        // x^T frags: one swizzled 16B blk per tile
    #pragma unroll
    for (int nt = 0; nt < 5; ++nt) {
        int c  = wv * 16 + m16;
        int p0 = koff(nt) + quad * 8;
        bfragX[nt] = *(const bf16x8*)(&xwT[c * 128 + (((p0 >> 3) ^ (c & 15)) << 3)]);
    }
    #pragma unroll
    for (int it = 0; it < 2; ++it) {
        int t = it * 256 + tid;
        if (t < 432) {                       // (win, h, p): 8*6*9
            int win  = t / 54;
            int rest = t - win * 54;
            int h = rest / 9;
            int p = rest - h * 9;
            const __bf16* a = &attnS[win * 486 + h * 81 + p * 9];
            float v[9];
            float m = -1e30f;
            #pragma unroll
            for (int q = 0; q < 9; ++q) { v[q] = (float)a[q]; m = fmaxf(m, v[q]); }
            float ssum = 0.f;
            #pragma unroll
            for (int q = 0; q < 9; ++q) { v[q] = __expf(v[q] - m); ssum += v[q]; }
            float inv = 1.f / ssum;
            int R  = win * 10 + p;
            int tt = R >> 4;
            int rl = R & 15;
            __bf16* dst = &bd[((h * 5 + tt) * 16 + rl) * 36 + win * 10 - koff(tt)];
            #pragma unroll
            for (int q = 0; q < 9; ++q) dst[q] = (__bf16)(v[q] * inv);
        }
    }
    __syncthreads();

    float bias[3];
    #pragma unroll
    for (int nt = 0; nt < 3; ++nt) bias[nt] = out_b[wv * 48 + nt * 16 + m16];

    floatx4 accF[5][3];
    #pragma unroll
    for (int mt = 0; mt < 5; ++mt)
        #pragma unroll
        for (int nt = 0; nt < 3; ++nt) {
            accF[mt][nt][0] = 0.f; accF[mt][nt][1] = 0.f;
            accF[mt][nt][2] = 0.f; accF[mt][nt][3] = 0.f;
        }

    const __bf16* Wt = (const __bf16*)g_WT;

    // --- B(0): P^T = x^T @ attn_0^T -> Ph0 ---
    {
        floatx4 accP[5];
        #pragma unroll
        for (int nt = 0; nt < 5; ++nt) {
            accP[nt][0] = 0.f; accP[nt][1] = 0.f;
            accP[nt][2] = 0.f; accP[nt][3] = 0.f;
            bf16x8 bfrag = ld_b64x2(&bd[((0 * 5 + nt) * 16 + m16) * 36 + quad * 8]);
            accP[nt] = __builtin_amdgcn_mfma_f32_16x16x32_bf16(bfragX[nt], bfrag, accP[nt], 0, 0, 0);
        }
        #pragma unroll
        for (int nt = 0; nt < 5; ++nt) {
            bf16x4 pk;
            #pragma unroll
            for (int r = 0; r < 4; ++r) pk[r] = (__bf16)accP[nt][r];
            *(bf16x4*)(&ph0b[(nt * 16 + m16) * 68 + wv * 16 + quad * 4]) = pk;
        }
    }
    __syncthreads();

    // --- Head loop: C(h) || B(h+1); ONE barrier per head ---
    #pragma unroll
    for (int h = 0; h < 6; ++h) {
        const __bf16* PhR = (h & 1) ? ph1b : ph0b;

        // C(h): accF += P_h @ W_h   (M=80, N=192 split 48/wave, K=64)
        #pragma unroll
        for (int ks = 0; ks < 2; ++ks) {
            bf16x8 bw[3];
            #pragma unroll
            for (int nt = 0; nt < 3; ++nt)
                bw[nt] = *(const bf16x8*)(Wt + (wv * 48 + nt * 16 + m16) * 384 + h * 64 + ks * 32 + quad * 8);
            #pragma unroll
            for (int mt = 0; mt < 5; ++mt) {
                bf16x8 af = ld_b64x2(&PhR[(mt * 16 + m16) * 68 + ks * 32 + quad * 8]);
                #pragma unroll
                for (int nt = 0; nt < 3; ++nt)
                    accF[mt][nt] = __builtin_amdgcn_mfma_f32_16x16x32_bf16(af, bw[nt], accF[mt][nt], 0, 0, 0);
            }
        }

        // B(h+1): P^T -> the other Ph buffer (independent of C(h))
        if (h < 5) {
            __bf16* PhW = (h & 1) ? ph0b : ph1b;
            floatx4 accP[5];
            #pragma unroll
            for (int nt = 0; nt < 5; ++nt) {
                accP[nt][0] = 0.f; accP[nt][1] = 0.f;
                accP[nt][2] = 0.f; accP[nt][3] = 0.f;
                bf16x8 bfrag = ld_b64x2(&bd[(((h + 1) * 5 + nt) * 16 + m16) * 36 + quad * 8]);
                accP[nt] = __builtin_amdgcn_mfma_f32_16x16x32_bf16(bfragX[nt], bfrag, accP[nt], 0, 0, 0);
            }
            #pragma unroll
            for (int nt = 0; nt < 5; ++nt) {
                bf16x4 pk;
                #pragma unroll
                for (int r = 0; r < 4; ++r) pk[r] = (__bf16)accP[nt][r];
                *(bf16x4*)(&PhW[(nt * 16 + m16) * 68 + wv * 16 + quad * 4]) = pk;
            }
            __syncthreads();
        }
    }

    // --- Epilogue: fp32 scatter stores, skip pad rows (p == 9) ---
    const int obase = ((bB * NH + iB * 3) * NW + jB * 3) * NE;
    #pragma unroll
    for (int mt = 0; mt < 5; ++mt)
        #pragma unroll
        for (int r = 0; r < 4; ++r) {
            int row = mt * 16 + quad * 4 + r;
            int win = row / 10;
            int p   = row - win * 10;
            if (p < 9) {
                int pr = p / 3;
                int pc = p - pr * 3;
                int base = obase + (pr * NW + win * 3 + pc) * NE;
                #pragma unroll
                for (int nt = 0; nt < 3; ++nt)
                    out[base + wv * 48 + nt * 16 + m16] = accF[mt][nt][r] + bias[nt];
            }
        }
}

extern "C" void kernel_launch(void* const* d_in, const int* in_sizes, int n_in,
                              void* d_out, int out_size, void* d_ws, size_t ws_size,
                              hipStream_t stream)
{
    const float* x      = (const float*)d_in[0];
    const float* v_w    = (const float*)d_in[1];
    const float* attn_w = (const float*)d_in[2];
    const float* attn_b = (const float*)d_in[3];
    const float* out_w  = (const float*)d_in[4];
    const float* out_b  = (const float*)d_in[5];
    float* out = (float*)d_out;
    (void)d_ws; (void)ws_size; (void)in_sizes; (void)n_in; (void)out_size;

    // 410 blocks cover NE*384 + NO*64 = 104832 prep elements
    hipLaunchKernelGGL(kt_prep, dim3(410), dim3(256), 0, stream, v_w, out_w, attn_w);
    hipLaunchKernelGGL(ka_fused, dim3(NWIN / 8), dim3(256), 0, stream,
                       x, attn_b, out_b, out);
}